// Round 3
// baseline (293.555 us; speedup 1.0000x reference)
//
#include <hip/hip_runtime.h>
#include <stdint.h>

constexpr int S = 1024;
constexpr int D = 1024;
constexpr int NB = 8;

typedef __bf16 bf16x8 __attribute__((ext_vector_type(8)));
typedef float floatx4 __attribute__((ext_vector_type(4)));

#define AS1 __attribute__((address_space(1)))
#define AS3 __attribute__((address_space(3)))

__device__ __forceinline__ unsigned short f2bf(float f) {
  unsigned u = __builtin_bit_cast(unsigned, f);
  u += 0x7fffu + ((u >> 16) & 1u);  // RNE
  return (unsigned short)(u >> 16);
}

__device__ __forceinline__ void gload16(const void* g, void* l) {
  __builtin_amdgcn_global_load_lds((const AS1 unsigned int*)g, (AS3 unsigned int*)l, 16, 0, 0);
}

// ---------------- prep: cast both inputs to bf16 + transpose 3 weights ----------------
__global__ __launch_bounds__(256) void prep_kernel(const float4* __restrict__ hs4,
                                                   const float4* __restrict__ rhs4,
                                                   ushort4* __restrict__ hsb4,
                                                   ushort4* __restrict__ rhsb4, int n4,
                                                   const float* __restrict__ Wq,
                                                   const float* __restrict__ Wk,
                                                   const float* __restrict__ Wv,
                                                   unsigned short* __restrict__ Wcat) {
  __shared__ float tile[32][33];
  const int bid = blockIdx.x;
  if (bid < 16384) {
    int i = bid * 256 + threadIdx.x;
    const float4* src;
    ushort4* dst;
    int j;
    if (i < n4) {
      src = hs4; dst = hsb4; j = i;
    } else {
      src = rhs4; dst = rhsb4; j = i - n4;
    }
    float4 v = src[j];
    ushort4 o;
    o.x = f2bf(v.x); o.y = f2bf(v.y); o.z = f2bf(v.z); o.w = f2bf(v.w);
    dst[j] = o;
  } else {
    const int t = bid - 16384;  // 0..3071
    const int z = t >> 10;
    const int r = t & 1023;
    const float* W = (z == 0) ? Wq : (z == 1) ? Wk : Wv;
    unsigned short* Wt = Wcat + (long long)z * D * D;
    const int bx = (r & 31) * 32;  // n block
    const int by = (r >> 5) * 32;  // k block
    const int x = threadIdx.x & 31;
    const int y0 = threadIdx.x >> 5;
    for (int i = 0; i < 4; ++i) {
      int y = y0 + i * 8;
      tile[y][x] = W[(by + y) * D + bx + x];
    }
    __syncthreads();
    for (int i = 0; i < 4; ++i) {
      int y = y0 + i * 8;
      Wt[(long long)(bx + y) * D + by + x] = f2bf(tile[x][y]);
    }
  }
}

// ====== 8-phase 256x128 GEMM core (T3+T4+T5): BK=64, dbuf LDS, counted vmcnt ======
// 512 threads = 8 waves (2M x 4N). Per-wave output 128x32 (acc[8][2] of 16x16 frags).
// LDS (ushort): buf*24576 | A: kk*8192 + row*32 + chunk*8   (256 rows x 32 cols/kk-half)
//                         | B: 16384 + kk*4096 + row*32 + chunk*8  (128 rows)
// Chunk swizzle (proven, 0 conflicts): phys16B-chunk = logical ^ ((row>>1)&3); staging
// pre-swizzles the GLOBAL source column so gload_lds dest stays linear (rule #21).
// Per K-tile: 4 phases {ds_read subtile; stage 1 half-tile; barrier; lgkm0; 8 MFMA; barrier}.
// Half-tile issue order: A0(2 loads) B0(1) A1(2) B1(1) = 6/tile.  vmcnt(3) at phases 1,3:
//   W1 retires A1,B1 of CURRENT tile (read in ph2/3); W2 retires A0,B0 of NEXT tile
//   (read in next ph0/1). 3 newest loads always stay in flight -> loads span barriers.
// Last tile restages itself into the dead buffer (uniform counts).

#define G8_IDX                                   \
  const int tid = threadIdx.x;                   \
  const int lane = tid & 63;                     \
  const int w = tid >> 6;                        \
  const int wr = w >> 2;                         \
  const int wc = w & 3;                          \
  const int r15 = lane & 15;                     \
  const int quad = lane >> 4;                    \
  const int pq = (quad ^ ((r15 >> 1) & 3)) * 8;  \
  const int srow = tid >> 2;                     \
  const int scg = (((tid & 3) ^ ((srow >> 1) & 3)) * 8);

#define G8_STAGE_SETUP(Abase, lda_, Bbase, ldb_)                        \
  const unsigned short* aG = (Abase) + (long long)srow * (lda_) + scg;  \
  const long long aR2 = (long long)128 * (lda_);                        \
  const unsigned short* bG = (Bbase) + (long long)srow * (ldb_) + scg;

#define G8_STAGE_A(BUF, kk, ko)                                                       \
  gload16(aG + (ko) + (kk) * 32, Sh + (BUF) * 24576 + (kk) * 8192 + w * 512);         \
  gload16(aG + (ko) + (kk) * 32 + aR2, Sh + (BUF) * 24576 + (kk) * 8192 + w * 512 + 4096);
#define G8_STAGE_B(BUF, kk, ko)                                                       \
  gload16(bG + (ko) + (kk) * 32, Sh + (BUF) * 24576 + 16384 + (kk) * 4096 + w * 512);

#define G8_LDA(BUF, kk, row) \
  (*reinterpret_cast<const bf16x8*>(Sh + (BUF) * 24576 + (kk) * 8192 + (row) * 32 + pq))
#define G8_LDB(BUF, kk, row) \
  (*reinterpret_cast<const bf16x8*>(Sh + (BUF) * 24576 + 16384 + (kk) * 4096 + (row) * 32 + pq))

#define G8_MFMA8(ACCOFF, AFR, BFR)                                              \
  __builtin_amdgcn_s_setprio(1);                                                \
  _Pragma("unroll") for (int mf = 0; mf < 4; ++mf)                              \
  _Pragma("unroll") for (int nf = 0; nf < 2; ++nf)                              \
      acc[(ACCOFF) + mf][nf] = __builtin_amdgcn_mfma_f32_16x16x32_bf16(         \
          AFR[mf], BFR[nf], acc[(ACCOFF) + mf][nf], 0, 0, 0);                   \
  __builtin_amdgcn_s_setprio(0);

#define G8_TILE(CUR, T)                                                         \
  {                                                                             \
    const int tn_ = ((T) + 1 < 16) ? (T) + 1 : (T);                             \
    const long long knx_ = (long long)tn_ * 64;                                 \
    bf16x8 a_[4], b0_[2], b1_[2];                                               \
    /* phase 0: compute (h0,kk0); stage A-kk0(next) */                          \
    _Pragma("unroll") for (int mf = 0; mf < 4; ++mf)                            \
        a_[mf] = G8_LDA(CUR, 0, wr * 128 + mf * 16 + r15);                      \
    _Pragma("unroll") for (int nf = 0; nf < 2; ++nf)                            \
        b0_[nf] = G8_LDB(CUR, 0, wc * 32 + nf * 16 + r15);                      \
    G8_STAGE_A((CUR) ^ 1, 0, knx_)                                              \
    __builtin_amdgcn_s_barrier();                                               \
    asm volatile("s_waitcnt lgkmcnt(0)" ::: "memory");                          \
    G8_MFMA8(0, a_, b0_)                                                        \
    __builtin_amdgcn_s_barrier();                                               \
    /* phase 1: compute (h1,kk0); stage B-kk0(next); W1 */                      \
    _Pragma("unroll") for (int mf = 0; mf < 4; ++mf)                            \
        a_[mf] = G8_LDA(CUR, 0, wr * 128 + 64 + mf * 16 + r15);                 \
    G8_STAGE_B((CUR) ^ 1, 0, knx_)                                              \
    asm volatile("s_waitcnt vmcnt(3)" ::: "memory");                            \
    __builtin_amdgcn_s_barrier();                                               \
    asm volatile("s_waitcnt lgkmcnt(0)" ::: "memory");                          \
    G8_MFMA8(4, a_, b0_)                                                        \
    __builtin_amdgcn_s_barrier();                                               \
    /* phase 2: compute (h0,kk1); stage A-kk1(next) */                          \
    _Pragma("unroll") for (int mf = 0; mf < 4; ++mf)                            \
        a_[mf] = G8_LDA(CUR, 1, wr * 128 + mf * 16 + r15);                      \
    _Pragma("unroll") for (int nf = 0; nf < 2; ++nf)                            \
        b1_[nf] = G8_LDB(CUR, 1, wc * 32 + nf * 16 + r15);                      \
    G8_STAGE_A((CUR) ^ 1, 1, knx_)                                              \
    __builtin_amdgcn_s_barrier();                                               \
    asm volatile("s_waitcnt lgkmcnt(0)" ::: "memory");                          \
    G8_MFMA8(0, a_, b1_)                                                        \
    __builtin_amdgcn_s_barrier();                                               \
    /* phase 3: compute (h1,kk1); stage B-kk1(next); W2 */                      \
    _Pragma("unroll") for (int mf = 0; mf < 4; ++mf)                            \
        a_[mf] = G8_LDA(CUR, 1, wr * 128 + 64 + mf * 16 + r15);                 \
    G8_STAGE_B((CUR) ^ 1, 1, knx_)                                              \
    asm volatile("s_waitcnt vmcnt(3)" ::: "memory");                            \
    __builtin_amdgcn_s_barrier();                                               \
    asm volatile("s_waitcnt lgkmcnt(0)" ::: "memory");                          \
    G8_MFMA8(4, a_, b1_)                                                        \
    __builtin_amdgcn_s_barrier();                                               \
  }

#define G8_KLOOP                                       \
  G8_STAGE_A(0, 0, 0)                                  \
  G8_STAGE_B(0, 0, 0)                                  \
  G8_STAGE_A(0, 1, 0)                                  \
  G8_STAGE_B(0, 1, 0)                                  \
  asm volatile("s_waitcnt vmcnt(3)" ::: "memory");     \
  __builtin_amdgcn_s_barrier();                        \
  for (int t = 0; t < 16; t += 2) {                    \
    G8_TILE(0, t)                                      \
    G8_TILE(1, t + 1)                                  \
  }

#define G8_ACC_INIT                    \
  floatx4 acc[8][2];                   \
  _Pragma("unroll") for (int i = 0; i < 8; ++i)        \
  _Pragma("unroll") for (int j = 0; j < 2; ++j) acc[i][j] = {0.f, 0.f, 0.f, 0.f};

// ---------------- fused QKV GEMM: M=8192, N=3072, 768 blocks ----------------
__global__ __launch_bounds__(512, 2) void gemm_qkv_kernel(
    const unsigned short* __restrict__ hsb, const unsigned short* __restrict__ rhsb,
    const unsigned short* __restrict__ Wcat, unsigned short* __restrict__ Qm,
    unsigned short* __restrict__ Km, unsigned short* __restrict__ Vmt,
    const float* __restrict__ bq, const float* __restrict__ bk, const float* __restrict__ bv) {
  __shared__ __align__(16) unsigned short Sh[49152];  // 96 KB
  G8_IDX
  const int bid = blockIdx.x;                   // 0..767
  const int swz = (bid & 7) * 96 + (bid >> 3);  // XCD-contiguous
  const int bx = swz % 24;                      // n tile (128)
  const int by = swz / 24;                      // m tile (256)
  const long long n0g = (long long)bx * 128;
  const int seg = bx >> 3;                      // 0=Q 1=K 2=V
  const long long m0 = (long long)by * 256;
  const unsigned short* A = ((seg == 0) ? hsb : rhsb) + m0 * D;
  const unsigned short* Bt = Wcat + n0g * D;
  const float* bias = (seg == 0) ? bq : (seg == 1) ? bk : bv;

  G8_STAGE_SETUP(A, D, Bt, D)
  G8_ACC_INIT
  G8_KLOOP

  const long long nloc0 = n0g & 1023;
  for (int i = 0; i < 8; ++i) {
    for (int nf = 0; nf < 2; ++nf) {
      const long long mrow = m0 + wr * 128 + i * 16 + quad * 4;
      const long long nc = nloc0 + wc * 32 + nf * 16 + r15;
      const float bval = bias[nc];
      floatx4 v = acc[i][nf];
      for (int e = 0; e < 4; ++e) {
        float val = v[e] + bval;
        long long m = mrow + e;
        if (seg == 0) {
          Qm[m * D + nc] = f2bf(val);
        } else if (seg == 1) {
          Km[m * D + nc] = f2bf(val);
        } else {
          Vmt[(m >> 10) * (long long)(S * D) + nc * S + (m & 1023)] = f2bf(val);
        }
      }
    }
  }
}

// ------- scores GEMM + fused mask/exp + partial row sums; 256 blocks, batch-per-XCD ------
// rowsumP[z][slot=bx*4+wc][row]: 32 per-32-col partials per row (1 MB total).
__global__ __launch_bounds__(512, 2) void gemm_scores_kernel(
    const unsigned short* __restrict__ Qm, const unsigned short* __restrict__ Km,
    const float* __restrict__ mask, unsigned short* __restrict__ E,
    float* __restrict__ rowsumP) {
  __shared__ __align__(16) unsigned short Sh[49152];
  G8_IDX
  const int bid = blockIdx.x;  // 0..255
  const int z = bid & 7;       // batch == XCD
  const int r = bid >> 3;      // 0..31
  const int by = r >> 3;       // 0..3  (m tile, 256)
  const int bx = r & 7;        // 0..7  (n tile, 128)
  const long long m0 = (long long)by * 256;
  const long long n0 = (long long)bx * 128;
  const unsigned short* A = Qm + (long long)z * S * D + m0 * D;
  const unsigned short* Bt = Km + (long long)z * S * D + n0 * D;

  G8_STAGE_SETUP(A, D, Bt, D)
  G8_ACC_INIT
  G8_KLOOP

  const long long zE = (long long)z * S * 1024;
  float rowpart[8][4];
  for (int i = 0; i < 8; ++i)
    for (int e = 0; e < 4; ++e) rowpart[i][e] = 0.f;

  for (int i = 0; i < 8; ++i) {
    for (int nf = 0; nf < 2; ++nf) {
      const long long mrow = m0 + wr * 128 + i * 16 + quad * 4;
      const long long nc = n0 + wc * 32 + nf * 16 + r15;
      floatx4 v = acc[i][nf];
      for (int e = 0; e < 4; ++e) {
        long long m = mrow + e;
        float mval = mask[zE + m * 1024 + nc];
        float sc = v[e] * 0.125f + (1.0f - mval) * -1e9f;
        float Ev = __expf(sc);
        E[zE + m * 1024 + nc] = f2bf(Ev);
        rowpart[i][e] += Ev;
      }
    }
  }
  const int slot = bx * 4 + wc;  // 0..31
  for (int i = 0; i < 8; ++i) {
    for (int e = 0; e < 4; ++e) {
      float s = rowpart[i][e];
      s += __shfl_xor(s, 1, 64);
      s += __shfl_xor(s, 2, 64);
      s += __shfl_xor(s, 4, 64);
      s += __shfl_xor(s, 8, 64);
      if (r15 == 0) {
        int mloc = (int)(m0 + wr * 128 + i * 16 + quad * 4 + e);
        rowsumP[(z << 15) + (slot << 10) + mloc] = s;
      }
    }
  }
}

// ------- ctx GEMM: out = (E . Vmt^T) / rowsum, permuted store; 256 blocks ---------
__global__ __launch_bounds__(512, 2) void gemm_ctx_kernel(const unsigned short* __restrict__ E,
                                                          const unsigned short* __restrict__ Vmt,
                                                          const float* __restrict__ rowsumP,
                                                          float* __restrict__ out) {
  __shared__ __align__(16) unsigned short Sh[49152];
  __shared__ float rsinv[256];
  G8_IDX
  const int bid = blockIdx.x;
  const int z = bid & 7;
  const int r = bid >> 3;
  const int by = r >> 3;
  const int bx = r & 7;
  const long long m0 = (long long)by * 256;
  const long long n0 = (long long)bx * 128;
  const unsigned short* A = E + (long long)z * S * 1024 + m0 * 1024;
  const unsigned short* Bt = Vmt + (long long)z * S * D + n0 * D;

  if (tid < 256) {  // sum the 32 partial row sums; invert once
    float s = 0.f;
    for (int t = 0; t < 32; ++t) s += rowsumP[(z << 15) + (t << 10) + (int)m0 + tid];
    rsinv[tid] = 1.0f / s;
  }
  __syncthreads();  // before any staging is in flight: full drain is free here

  G8_STAGE_SETUP(A, 1024, Bt, D)
  G8_ACC_INIT
  G8_KLOOP

  for (int i = 0; i < 8; ++i) {
    for (int nf = 0; nf < 2; ++nf) {
      const int r0 = wr * 128 + i * 16 + quad * 4;
      const long long ncol = n0 + wc * 32 + nf * 16 + r15;
      floatx4 v = acc[i][nf];
      for (int e = 0; e < 4; ++e) {
        long long m = m0 + r0 + e;
        float val = v[e] * rsinv[r0 + e];
        out[(long long)z * S * D + (ncol >> 6) * (long long)(S * 64) + m * 64 + (ncol & 63)] =
            val;
      }
    }
  }
}

extern "C" void kernel_launch(void* const* d_in, const int* in_sizes, int n_in, void* d_out,
                              int out_size, void* d_ws, size_t ws_size, hipStream_t stream) {
  const float* hs = (const float*)d_in[0];
  const float* rhs = (const float*)d_in[1];
  const float* mask = (const float*)d_in[2];
  const float* Wq = (const float*)d_in[3];
  const float* bq = (const float*)d_in[4];
  const float* Wk = (const float*)d_in[5];
  const float* bk = (const float*)d_in[6];
  const float* Wv = (const float*)d_in[7];
  const float* bv = (const float*)d_in[8];
  float* out = (float*)d_out;
  char* ws = (char*)d_ws;
  const size_t MB = 1ull << 20;
  // layout: Wcat(6MB) | hsb(16) | rhsb(16) | Qm(16) | Km(16) | Vmt(16) = 86 MB.
  // E (16MB bf16) overlays hsb (dead after QKV); rowsumP (1MB) overlays rhsb (dead after QKV).
  unsigned short* Wcat = (unsigned short*)(ws + 0 * MB);
  unsigned short* hsb = (unsigned short*)(ws + 6 * MB);
  unsigned short* rhsb = (unsigned short*)(ws + 22 * MB);
  unsigned short* Qm = (unsigned short*)(ws + 38 * MB);
  unsigned short* Km = (unsigned short*)(ws + 54 * MB);
  unsigned short* Vmt = (unsigned short*)(ws + 70 * MB);
  unsigned short* E = (unsigned short*)(ws + 6 * MB);
  float* rowsumP = (float*)(ws + 22 * MB);

  const int n4 = NB * S * D / 4;  // 2M float4 per input
  prep_kernel<<<16384 + 3072, 256, 0, stream>>>((const float4*)hs, (const float4*)rhs,
                                                (ushort4*)hsb, (ushort4*)rhsb, n4, Wq, Wk, Wv,
                                                Wcat);

  // fused QKV projections: 256x128 tiles, 8-phase counted-vmcnt schedule
  gemm_qkv_kernel<<<dim3(768), 512, 0, stream>>>(hsb, rhsb, Wcat, Qm, Km, Vmt, bq, bk, bv);

  // E[b] = exp(mask(Qm[b].Km[b]^T/8)) + partial row sums (softmax folded in)
  gemm_scores_kernel<<<dim3(256), 512, 0, stream>>>(Qm, Km, mask, E, rowsumP);

  // ctx[b] = (E[b].Vmt[b]^T)/rowsum, permuted fp32 store into d_out
  gemm_ctx_kernel<<<dim3(256), 512, 0, stream>>>(E, Vmt, rowsumP, out);
}

// Round 4
// 293.003 us; speedup vs baseline: 1.0019x; 1.0019x over previous
//
#include <hip/hip_runtime.h>
#include <stdint.h>

constexpr int S = 1024;
constexpr int D = 1024;
constexpr int NB = 8;

typedef __bf16 bf16x8 __attribute__((ext_vector_type(8)));
typedef float floatx4 __attribute__((ext_vector_type(4)));

#define AS1 __attribute__((address_space(1)))
#define AS3 __attribute__((address_space(3)))

__device__ __forceinline__ unsigned short f2bf(float f) {
  unsigned u = __builtin_bit_cast(unsigned, f);
  u += 0x7fffu + ((u >> 16) & 1u);  // RNE
  return (unsigned short)(u >> 16);
}

__device__ __forceinline__ void gload16(const void* g, void* l) {
  __builtin_amdgcn_global_load_lds((const AS1 unsigned int*)g, (AS3 unsigned int*)l, 16, 0, 0);
}

// ---------------- prep: cast both inputs to bf16 + transpose 3 weights ----------------
__global__ __launch_bounds__(256) void prep_kernel(const float4* __restrict__ hs4,
                                                   const float4* __restrict__ rhs4,
                                                   ushort4* __restrict__ hsb4,
                                                   ushort4* __restrict__ rhsb4, int n4,
                                                   const float* __restrict__ Wq,
                                                   const float* __restrict__ Wk,
                                                   const float* __restrict__ Wv,
                                                   unsigned short* __restrict__ Wcat) {
  __shared__ float tile[32][33];
  const int bid = blockIdx.x;
  if (bid < 16384) {
    int i = bid * 256 + threadIdx.x;
    const float4* src;
    ushort4* dst;
    int j;
    if (i < n4) {
      src = hs4; dst = hsb4; j = i;
    } else {
      src = rhs4; dst = rhsb4; j = i - n4;
    }
    float4 v = src[j];
    ushort4 o;
    o.x = f2bf(v.x); o.y = f2bf(v.y); o.z = f2bf(v.z); o.w = f2bf(v.w);
    dst[j] = o;
  } else {
    const int t = bid - 16384;  // 0..3071
    const int z = t >> 10;
    const int r = t & 1023;
    const float* W = (z == 0) ? Wq : (z == 1) ? Wk : Wv;
    unsigned short* Wt = Wcat + (long long)z * D * D;
    const int bx = (r & 31) * 32;  // n block
    const int by = (r >> 5) * 32;  // k block
    const int x = threadIdx.x & 31;
    const int y0 = threadIdx.x >> 5;
    for (int i = 0; i < 4; ++i) {
      int y = y0 + i * 8;
      tile[y][x] = W[(by + y) * D + bx + x];
    }
    __syncthreads();
    for (int i = 0; i < 4; ++i) {
      int y = y0 + i * 8;
      Wt[(long long)(bx + y) * D + by + x] = f2bf(tile[x][y]);
    }
  }
}

// ====== GEMM core (R0-proven loop): 128x128 tile, BK=32, global_load_lds, 2 barriers ======
// Source-chunk XOR swizzle: lane (row, c) loads global chunk c^((row>>1)&3) into LDS chunk c
// (same 64B line per 4-lane group -> coalescing preserved). Reader: physical chunk =
// quad ^ ((r15>>1)&3), so data read = global chunk `quad` (XOR cancels) -> conflict-free.

#define GEMM_STAGE_SETUP(Abase, lda_, Bbase, ldb_)                            \
  const int srow = tid >> 2;                                                  \
  const int scg = (((tid & 3) ^ ((srow >> 1) & 3)) * 8);                      \
  const unsigned short* aG0 = (Abase) + (long long)srow * (lda_) + scg;       \
  const unsigned short* aG1 = aG0 + (long long)64 * (lda_);                   \
  const unsigned short* bG0 = (Bbase) + (long long)srow * (ldb_) + scg;       \
  const unsigned short* bG1 = bG0 + (long long)64 * (ldb_);                   \
  unsigned short* aL0 = As + w * 512;                                         \
  unsigned short* aL1 = As + w * 512 + 2048;                                  \
  unsigned short* bL0 = Bs + w * 512;                                         \
  unsigned short* bL1 = Bs + w * 512 + 2048;

#define GEMM_KLOOP(Klen)                                                               \
  for (int k0 = 0; k0 < (Klen); k0 += 32) {                                            \
    gload16(aG0 + k0, aL0);                                                            \
    gload16(aG1 + k0, aL1);                                                            \
    gload16(bG0 + k0, bL0);                                                            \
    gload16(bG1 + k0, bL1);                                                            \
    __syncthreads();                                                                   \
    bf16x8 af[4], bfr[4];                                                              \
    for (int t = 0; t < 4; ++t) {                                                      \
      af[t] = *reinterpret_cast<const bf16x8*>(As + (wm + t * 16 + r15) * 32 + pq);    \
      bfr[t] = *reinterpret_cast<const bf16x8*>(Bs + (wn + t * 16 + r15) * 32 + pq);   \
    }                                                                                  \
    for (int mt = 0; mt < 4; ++mt)                                                     \
      for (int nt = 0; nt < 4; ++nt)                                                   \
        acc[mt][nt] =                                                                  \
            __builtin_amdgcn_mfma_f32_16x16x32_bf16(af[mt], bfr[nt], acc[mt][nt], 0, 0, 0); \
    __syncthreads();                                                                   \
  }

#define GEMM_COMMON_IDX                  \
  const int tid = threadIdx.x;           \
  const int lane = tid & 63;             \
  const int w = tid >> 6;                \
  const int r15 = lane & 15;             \
  const int quad = lane >> 4;            \
  const int pq = (quad ^ ((r15 >> 1) & 3)) * 8; \
  const int wm = (w >> 1) * 64;          \
  const int wn = (w & 1) * 64;

#define GEMM_ACC_INIT                    \
  floatx4 acc[4][4];                     \
  for (int i = 0; i < 4; ++i)            \
    for (int j = 0; j < 4; ++j) acc[i][j] = {0.f, 0.f, 0.f, 0.f};

// ---------------- projection GEMM (one segment): M=8192, N=1024 ----------------
// Grid 512 (= 64 m-tiles x 8 n-tiles), XCD swizzle: XCD k owns m-tiles 8k..8k+7 x ALL
// n-tiles -> per-XCD L2 footprint = 8 A-panels (2MB) + full weight slice (2MB). Without
// this, bx-fastest dispatch spreads one A-panel's 8 consumers over 8 XCDs (A fetched ~8x).
__global__ __launch_bounds__(256) void gemm_proj_kernel(
    const unsigned short* __restrict__ Abase, const unsigned short* __restrict__ Wseg,
    const float* __restrict__ bias, unsigned short* __restrict__ dst, int vmode) {
  __shared__ __align__(16) unsigned short As[128 * 32];
  __shared__ __align__(16) unsigned short Bs[128 * 32];
  GEMM_COMMON_IDX
  const int bid = blockIdx.x;  // 0..511
  const int xcd = bid & 7;
  const int idx = bid >> 3;    // 0..63
  const int by = xcd * 8 + (idx >> 3);
  const int bx = idx & 7;
  const long long m0 = (long long)by * 128;
  const long long n0 = (long long)bx * 128;
  const unsigned short* A = Abase + m0 * D;
  const unsigned short* Bt = Wseg + n0 * D;

  GEMM_STAGE_SETUP(A, D, Bt, D)
  GEMM_ACC_INIT
  GEMM_KLOOP(D)

  for (int mt = 0; mt < 4; ++mt) {
    for (int nt = 0; nt < 4; ++nt) {
      const long long mrow = m0 + wm + mt * 16 + quad * 4;
      const long long nc = n0 + wn + nt * 16 + r15;
      const float bval = bias[nc];
      floatx4 v = acc[mt][nt];
      for (int e = 0; e < 4; ++e) {
        float val = v[e] + bval;
        long long m = mrow + e;
        if (vmode == 0) {
          dst[m * D + nc] = f2bf(val);
        } else {
          dst[(m >> 10) * (long long)(S * D) + nc * S + (m & 1023)] = f2bf(val);
        }
      }
    }
  }
}

// ------- scores GEMM + fused mask/exp + partial row sums (no softmax kernel) ---------
// E[z][m][n] = exp(Q.K^T/8 + (1-mask)*-1e9)  [no max-subtraction: |scores| <~ 10, fp32-safe]
// rowsumP[z][ntile][half][row]: per-64-col partials; EACH WAVE (wn-half) writes its own slot.
// Batch-per-XCD swizzle: z = bid&7 -> XCD z holds ONLY batch z's Qm+Km (4MB, fits L2);
// E it writes stays resident for gemm_ctx (same mapping there).
__global__ __launch_bounds__(256) void gemm_scores_kernel(
    const unsigned short* __restrict__ Qm, const unsigned short* __restrict__ Km,
    const float* __restrict__ mask, unsigned short* __restrict__ E,
    float* __restrict__ rowsumP) {
  __shared__ __align__(16) unsigned short As[128 * 32];
  __shared__ __align__(16) unsigned short Bs[128 * 32];
  GEMM_COMMON_IDX
  const int bid = blockIdx.x;  // 0..511
  const int z = bid & 7;       // batch == XCD
  const int r = bid >> 3;      // 0..63
  const int by = r >> 3;
  const int bx = r & 7;
  const long long m0 = (long long)by * 128;  // row tile within batch
  const long long n0 = (long long)bx * 128;  // col tile within batch
  const unsigned short* A = Qm + (long long)z * S * D + m0 * D;
  const unsigned short* Bt = Km + (long long)z * S * D + n0 * D;

  GEMM_STAGE_SETUP(A, D, Bt, D)
  GEMM_ACC_INIT
  GEMM_KLOOP(D)

  const long long zE = (long long)z * S * 1024;
  float rowpart[4][4];
  for (int mt = 0; mt < 4; ++mt)
    for (int e = 0; e < 4; ++e) rowpart[mt][e] = 0.f;

  for (int mt = 0; mt < 4; ++mt) {
    for (int nt = 0; nt < 4; ++nt) {
      const long long mrow = m0 + wm + mt * 16 + quad * 4;
      const long long nc = n0 + wn + nt * 16 + r15;
      floatx4 v = acc[mt][nt];
      for (int e = 0; e < 4; ++e) {
        long long m = mrow + e;
        float mval = mask[zE + m * 1024 + nc];
        float sc = v[e] * 0.125f + (1.0f - mval) * -1e9f;
        float Ev = __expf(sc);
        E[zE + m * 1024 + nc] = f2bf(Ev);
        rowpart[mt][e] += Ev;
      }
    }
  }
  // reduce each row's partials across the 16 r15-lanes of the quad (cols wn..wn+63)
  const int slot = (bx << 11) + ((wn >> 6) << 10);  // [ntile][half]
  for (int mt = 0; mt < 4; ++mt) {
    for (int e = 0; e < 4; ++e) {
      float s = rowpart[mt][e];
      s += __shfl_xor(s, 1, 64);
      s += __shfl_xor(s, 2, 64);
      s += __shfl_xor(s, 4, 64);
      s += __shfl_xor(s, 8, 64);
      if (r15 == 0) {
        int mloc = (int)(m0 + wm + mt * 16 + quad * 4 + e);
        rowsumP[(z << 14) + slot + mloc] = s;
      }
    }
  }
}

// ------- ctx GEMM: out = (E . Vmt^T) / rowsum, permuted store ---------
// Same batch-per-XCD swizzle as scores: E[z] (2MB) is re-read on the XCD that wrote it.
__global__ __launch_bounds__(256) void gemm_ctx_kernel(const unsigned short* __restrict__ E,
                                                       const unsigned short* __restrict__ Vmt,
                                                       const float* __restrict__ rowsumP,
                                                       float* __restrict__ out) {
  __shared__ __align__(16) unsigned short As[128 * 32];
  __shared__ __align__(16) unsigned short Bs[128 * 32];
  __shared__ float rsinv[128];
  GEMM_COMMON_IDX
  const int bid = blockIdx.x;  // 0..511
  const int z = bid & 7;
  const int r = bid >> 3;
  const int by = r >> 3;
  const int bx = r & 7;
  const long long m0 = (long long)by * 128;  // q-row tile
  const long long n0 = (long long)bx * 128;  // feature tile
  const unsigned short* A = E + (long long)z * S * 1024 + m0 * 1024;
  const unsigned short* Bt = Vmt + (long long)z * S * D + n0 * D;

  if (tid < 128) {  // sum the 16 partial row sums; invert once
    float s = 0.f;
    for (int t = 0; t < 16; ++t) s += rowsumP[(z << 14) + (t << 10) + (int)m0 + tid];
    rsinv[tid] = 1.0f / s;
  }

  GEMM_STAGE_SETUP(A, 1024, Bt, D)
  GEMM_ACC_INIT
  GEMM_KLOOP(1024)

  for (int mt = 0; mt < 4; ++mt) {
    for (int nt = 0; nt < 4; ++nt) {
      const int r0 = wm + mt * 16 + quad * 4;
      const long long ncol = n0 + wn + nt * 16 + r15;
      floatx4 v = acc[mt][nt];
      for (int e = 0; e < 4; ++e) {
        long long m = m0 + r0 + e;
        float val = v[e] * rsinv[r0 + e];
        out[(long long)z * S * D + (ncol >> 6) * (long long)(S * 64) + m * 64 + (ncol & 63)] =
            val;
      }
    }
  }
}

extern "C" void kernel_launch(void* const* d_in, const int* in_sizes, int n_in, void* d_out,
                              int out_size, void* d_ws, size_t ws_size, hipStream_t stream) {
  const float* hs = (const float*)d_in[0];
  const float* rhs = (const float*)d_in[1];
  const float* mask = (const float*)d_in[2];
  const float* Wq = (const float*)d_in[3];
  const float* bq = (const float*)d_in[4];
  const float* Wk = (const float*)d_in[5];
  const float* bk = (const float*)d_in[6];
  const float* Wv = (const float*)d_in[7];
  const float* bv = (const float*)d_in[8];
  float* out = (float*)d_out;
  char* ws = (char*)d_ws;
  const size_t MB = 1ull << 20;
  // layout: Wcat(6MB) | hsb(16) | rhsb(16) | Qm(16) | Km(16) | Vmt(16) = 86 MB.
  // E (16MB bf16) overlays hsb (dead after QKV); rowsumP (512KB) overlays rhsb (dead after QKV).
  unsigned short* Wcat = (unsigned short*)(ws + 0 * MB);
  unsigned short* hsb = (unsigned short*)(ws + 6 * MB);
  unsigned short* rhsb = (unsigned short*)(ws + 22 * MB);
  unsigned short* Qm = (unsigned short*)(ws + 38 * MB);
  unsigned short* Km = (unsigned short*)(ws + 54 * MB);
  unsigned short* Vmt = (unsigned short*)(ws + 70 * MB);
  unsigned short* E = (unsigned short*)(ws + 6 * MB);
  float* rowsumP = (float*)(ws + 22 * MB);

  const int n4 = NB * S * D / 4;  // 2M float4 per input
  prep_kernel<<<16384 + 3072, 256, 0, stream>>>((const float4*)hs, (const float4*)rhs,
                                                (ushort4*)hsb, (ushort4*)rhsb, n4, Wq, Wk, Wv,
                                                Wcat);

  // Q/K/V projections as 3 launches (XCD-local A panels + weight slice; also makes
  // per-kernel timings visible in the profile's top-5)
  gemm_proj_kernel<<<dim3(512), 256, 0, stream>>>(hsb, Wcat, bq, Qm, 0);
  gemm_proj_kernel<<<dim3(512), 256, 0, stream>>>(rhsb, Wcat + (long long)D * D, bk, Km, 0);
  gemm_proj_kernel<<<dim3(512), 256, 0, stream>>>(rhsb, Wcat + 2ll * D * D, bv, Vmt, 1);

  // E[b] = exp(mask(Qm[b].Km[b]^T/8)) + partial row sums (softmax folded in)
  gemm_scores_kernel<<<dim3(512), 256, 0, stream>>>(Qm, Km, mask, E, rowsumP);

  // ctx[b] = (E[b].Vmt[b]^T)/rowsum, permuted fp32 store into d_out
  gemm_ctx_kernel<<<dim3(512), 256, 0, stream>>>(E, Vmt, rowsumP, out);
}